// Round 12
// baseline (179.614 us; speedup 1.0000x reference)
//
#include <hip/hip_runtime.h>
#include <hip/hip_fp16.h>

// Problem constants (B,C,H,W = 2,3,96,96; D=32)
#define BB 2
#define CC 3
#define NN 9216   // 96*96
#define DD 32
#define NSPLIT 8                      // waves per block, split over keys
#define KEYS_PER_WAVE (NN / NSPLIT)   // 1152
#define CKEYS 96                      // keys per chunk (was 64) — fewer, fatter traversals
#define CHUNKS (KEYS_PER_WAVE / CKEYS) // 12
#define NBLK (CKEYS / 16)             // 6 16-key S-blocks per chunk
#define PSTRIDE 104                   // 96 + 8 pad: 52 dwords % 32 = 20 -> free 2-way banking
#define L2E 1.44269504f

typedef _Float16 half8 __attribute__((ext_vector_type(8)));
typedef _Float16 half4v __attribute__((ext_vector_type(4)));
typedef __fp16 fp16x2 __attribute__((ext_vector_type(2)));
typedef float float4v __attribute__((ext_vector_type(4)));

#define MFMA_K32(a, b, c) __builtin_amdgcn_mfma_f32_16x16x32_f16((a), (b), (c), 0, 0, 0)

// ---------------------------------------------------------------------------
// Fused prep. Blocks [0,288): QK — thread per (b, n, part), part = 8 channels
// of both f and g, hi/lo split. Query pre-scaled by log2(e) so QK^T emits
// scores directly in the log2 domain. Blocks [288,576): V — [B][D][N] fp16.
// ---------------------------------------------------------------------------
__global__ __launch_bounds__(256) void prep_kernel(
    const float* __restrict__ img,
    const float* __restrict__ kw, const float* __restrict__ kb,
    const float* __restrict__ qw, const float* __restrict__ qb,
    const float* __restrict__ vw, const float* __restrict__ vb,
    _Float16* __restrict__ fH, _Float16* __restrict__ fL,
    _Float16* __restrict__ gH, _Float16* __restrict__ gL,
    _Float16* __restrict__ hV)
{
    int bid = blockIdx.x;
    if (bid < 288) {
        int id = bid * 256 + threadIdx.x;          // [0, BB*NN*4)
        int part = id & 3;
        int n = (id >> 2) % NN;
        int b = (id >> 2) / NN;
        const float* xb = img + (size_t)b * CC * NN + n;
        float x0 = xb[0], x1 = xb[NN], x2 = xb[2 * NN];
        half8 fh, fl, gh, gl;
#pragma unroll
        for (int j = 0; j < 8; j++) {
            int d = part * 8 + j;
            float fv = kw[d * 3 + 0] * x0 + kw[d * 3 + 1] * x1 + kw[d * 3 + 2] * x2 + kb[d];
            float gv = (qw[d * 3 + 0] * x0 + qw[d * 3 + 1] * x1 + qw[d * 3 + 2] * x2 + qb[d]) * L2E;
            _Float16 fhi = (_Float16)fv;
            _Float16 ghi = (_Float16)gv;
            fh[j] = fhi; fl[j] = (_Float16)(fv - (float)fhi);
            gh[j] = ghi; gl[j] = (_Float16)(gv - (float)ghi);
        }
        size_t off = ((size_t)b * NN + n) * DD + part * 8;
        *(half8*)(fH + off) = fh;
        *(half8*)(fL + off) = fl;
        *(half8*)(gH + off) = gh;
        *(half8*)(gL + off) = gl;
    } else {
        int id = (bid - 288) * 256 + threadIdx.x;  // [0, BB*DD*NN/8)
        const int N8 = NN / 8;
        int n8 = id % N8;
        int d = (id / N8) % DD;
        int b = id / (N8 * DD);
        const float* xb = img + (size_t)b * CC * NN + n8 * 8;
        float w0 = vw[d * 3 + 0], w1 = vw[d * 3 + 1], w2 = vw[d * 3 + 2], bv = vb[d];
        half8 hv;
#pragma unroll
        for (int j = 0; j < 8; j++)
            hv[j] = (_Float16)(w0 * xb[j] + w1 * xb[NN + j] + w2 * xb[2 * NN + j] + bv);
        *(half8*)(hV + (size_t)id * 8) = hv;
    }
}

// ---------------------------------------------------------------------------
// Flash attention, split-K x8, TWO 16-query tiles per wave, 96-KEY CHUNKS:
// 12 dependency-chain traversals per wave instead of 18 — amortizes the
// per-chunk fixed latency F (the only lever that has moved the needle: R8).
//   S (K=32 MFMA): A = K, B = Q  => C[row=n=quad*4+r, col=m=l16].
//   P staged wave-privately in LDS [m][n] stride 104 (free 2-way banking).
//   PV (K=32 MFMA): A = V^T[d][n], B = P => C[row=d, col=m=l16]; softmax
//   alpha per-lane; rsum reduction deferred to merge.
//   launch_bounds(512,3): VGPR cap ~170 for ~156 live (K48+V24+Q32+acc16+s24).
// ---------------------------------------------------------------------------
__global__ __launch_bounds__(512, 3) void attn_kernel(
    const _Float16* __restrict__ fH, const _Float16* __restrict__ fL,
    const _Float16* __restrict__ gH, const _Float16* __restrict__ gL,
    const _Float16* __restrict__ hV,
    const float* __restrict__ ow, const float* __restrict__ ob,
    float* __restrict__ out)
{
    const int tile = blockIdx.x;           // 0 .. B*(N/32)-1
    const int b = tile / (NN / 32);
    const int m0 = (tile % (NN / 32)) * 32;
    const int tid = threadIdx.x;
    const int w = tid >> 6;                // wave id 0..7
    const int lane = tid & 63;
    const int l16 = lane & 15;
    const int quad = lane >> 4;

    // Phase union: P staging (8 waves x 2 tiles x 16 x 104 fp16 = 53248 B)
    // reused as the split-K merge accumulator (33792 B).
    union SMem {
        _Float16 P[NSPLIT * 2 * 16 * PSTRIDE];
        float acc[NSPLIT][DD][33];         // [w][d][m]
    };
    __shared__ __align__(16) SMem sm;
    __shared__ float mbuf[NSPLIT][32];     // [w][m]
    __shared__ float lbuf[NSPLIT][4][32];  // [w][quad][m] (quad-partial sums)
    __shared__ float vlds[DD][33];         // merged v^T [d][m]

    // Q B-fragments for both tiles (hi + lo, log2e-scaled)
    const _Float16* gHb = gH + ((size_t)b * NN + m0 + l16) * DD + quad * 8;
    const _Float16* gLb = gL + ((size_t)b * NN + m0 + l16) * DD + quad * 8;
    half8 qh0 = *(const half8*)(gHb);
    half8 ql0 = *(const half8*)(gLb);
    half8 qh1 = *(const half8*)(gHb + (size_t)16 * DD);
    half8 ql1 = *(const half8*)(gLb + (size_t)16 * DD);

    float4v acc00 = {0,0,0,0}, acc01 = {0,0,0,0};  // tile0: O^T[d=quad*4+r / +16][m=l16]
    float4v acc10 = {0,0,0,0}, acc11 = {0,0,0,0};  // tile1
    float mrun0 = -1e30f, lrun0 = 0.f;             // per-lane col stats (log2 dom.)
    float mrun1 = -1e30f, lrun1 = 0.f;             // lrun = quad-partial sum

    const int nbase = w * KEYS_PER_WAVE;
    const _Float16* hb = hV + (size_t)b * DD * NN;
    const _Float16* vp0 = hb + (size_t)l16 * NN + nbase + quad * 8;        // V^T rows d=l16
    const _Float16* vp1 = hb + (size_t)(l16 + 16) * NN + nbase + quad * 8; // rows d=l16+16
    const _Float16* khp = fH + ((size_t)b * NN + nbase + l16) * DD + quad * 8;
    const _Float16* klp = fL + ((size_t)b * NN + nbase + l16) * DD + quad * 8;
    _Float16* Pw0 = sm.P + (size_t)(w * 2 + 0) * 16 * PSTRIDE;
    _Float16* Pw1 = sm.P + (size_t)(w * 2 + 1) * 16 * PSTRIDE;

    for (int c = 0; c < CHUNKS; ++c) {
        // ---- shared K fragments (12 x b128) and V^T fragments (6 x b128)
        half8 ka[NBLK], kl[NBLK];
#pragma unroll
        for (int blk = 0; blk < NBLK; blk++) {
            ka[blk] = *(const half8*)(khp + (size_t)(c * CKEYS + blk * 16) * DD);
            kl[blk] = *(const half8*)(klp + (size_t)(c * CKEYS + blk * 16) * DD);
        }
        half8 v0[3], v1[3];                    // [n-group of 32][d lo/hi]
#pragma unroll
        for (int g = 0; g < 3; g++) {
            v0[g] = *(const half8*)(vp0 + c * CKEYS + g * 32);
            v1[g] = *(const half8*)(vp1 + c * CKEYS + g * 32);
        }

        // ================= tile 0: scores + softmax + P stage =================
        {
            float4v s[NBLK];
#pragma unroll
            for (int blk = 0; blk < NBLK; blk++) {
                float4v z = {0,0,0,0};
                float4v t = MFMA_K32(ka[blk], ql0, z);
                t = MFMA_K32(kl[blk], qh0, t);
                s[blk] = MFMA_K32(ka[blk], qh0, t);
            }
            float mx = -1e30f;
#pragma unroll
            for (int blk = 0; blk < NBLK; blk++) {
                float m01 = fmaxf(fmaxf(s[blk][0], s[blk][1]), fmaxf(s[blk][2], s[blk][3]));
                mx = fmaxf(mx, m01);
            }
            mx = fmaxf(mx, __shfl_xor(mx, 16, 64));
            mx = fmaxf(mx, __shfl_xor(mx, 32, 64));
            float mnew = fmaxf(mrun0, mx);
            float rsum = 0.f;
#pragma unroll
            for (int blk = 0; blk < NBLK; blk++) {
                float p0 = __builtin_amdgcn_exp2f(s[blk][0] - mnew);
                float p1 = __builtin_amdgcn_exp2f(s[blk][1] - mnew);
                float p2 = __builtin_amdgcn_exp2f(s[blk][2] - mnew);
                float p3 = __builtin_amdgcn_exp2f(s[blk][3] - mnew);
                union { fp16x2 h2[2]; half4v h4; } u;
                u.h2[0] = __builtin_amdgcn_cvt_pkrtz(p0, p1);
                u.h2[1] = __builtin_amdgcn_cvt_pkrtz(p2, p3);
                *(half4v*)(Pw0 + l16 * PSTRIDE + blk * 16 + quad * 4) = u.h4;
                rsum += (p0 + p1) + (p2 + p3);
            }
            if (__any(mnew > mrun0)) {
                float alpha = __builtin_amdgcn_exp2f(mrun0 - mnew);
#pragma unroll
                for (int r = 0; r < 4; r++) { acc00[r] *= alpha; acc01[r] *= alpha; }
                lrun0 = lrun0 * alpha + rsum;
                mrun0 = mnew;
            } else {
                lrun0 += rsum;
            }
        }
        // ================= tile 1: scores + softmax + P stage =================
        {
            float4v s[NBLK];
#pragma unroll
            for (int blk = 0; blk < NBLK; blk++) {
                float4v z = {0,0,0,0};
                float4v t = MFMA_K32(ka[blk], ql1, z);
                t = MFMA_K32(kl[blk], qh1, t);
                s[blk] = MFMA_K32(ka[blk], qh1, t);
            }
            float mx = -1e30f;
#pragma unroll
            for (int blk = 0; blk < NBLK; blk++) {
                float m01 = fmaxf(fmaxf(s[blk][0], s[blk][1]), fmaxf(s[blk][2], s[blk][3]));
                mx = fmaxf(mx, m01);
            }
            mx = fmaxf(mx, __shfl_xor(mx, 16, 64));
            mx = fmaxf(mx, __shfl_xor(mx, 32, 64));
            float mnew = fmaxf(mrun1, mx);
            float rsum = 0.f;
#pragma unroll
            for (int blk = 0; blk < NBLK; blk++) {
                float p0 = __builtin_amdgcn_exp2f(s[blk][0] - mnew);
                float p1 = __builtin_amdgcn_exp2f(s[blk][1] - mnew);
                float p2 = __builtin_amdgcn_exp2f(s[blk][2] - mnew);
                float p3 = __builtin_amdgcn_exp2f(s[blk][3] - mnew);
                union { fp16x2 h2[2]; half4v h4; } u;
                u.h2[0] = __builtin_amdgcn_cvt_pkrtz(p0, p1);
                u.h2[1] = __builtin_amdgcn_cvt_pkrtz(p2, p3);
                *(half4v*)(Pw1 + l16 * PSTRIDE + blk * 16 + quad * 4) = u.h4;
                rsum += (p0 + p1) + (p2 + p3);
            }
            if (__any(mnew > mrun1)) {
                float alpha = __builtin_amdgcn_exp2f(mrun1 - mnew);
#pragma unroll
                for (int r = 0; r < 4; r++) { acc10[r] *= alpha; acc11[r] *= alpha; }
                lrun1 = lrun1 * alpha + rsum;
                mrun1 = mnew;
            } else {
                lrun1 += rsum;
            }
        }
        // ---- PV: A = V^T (regs), B = P (LDS b128; compiler inserts lgkmcnt)
        //      => C[row=d, col=m] — per-lane stats, no shuffles
#pragma unroll
        for (int g = 0; g < 3; g++) {
            half8 pf = *(const half8*)(Pw0 + l16 * PSTRIDE + g * 32 + quad * 8);
            acc00 = MFMA_K32(v0[g], pf, acc00);
            acc01 = MFMA_K32(v1[g], pf, acc01);
        }
#pragma unroll
        for (int g = 0; g < 3; g++) {
            half8 qf = *(const half8*)(Pw1 + l16 * PSTRIDE + g * 32 + quad * 8);
            acc10 = MFMA_K32(v0[g], qf, acc10);
            acc11 = MFMA_K32(v1[g], qf, acc11);
        }
    }

    __syncthreads();   // all waves done with sm.P — safe to reuse as sm.acc

    // ---- write per-wave partials (fp32) for the split-K merge
    mbuf[w][l16]            = mrun0;   // quad-redundant, same value
    mbuf[w][l16 + 16]       = mrun1;
    lbuf[w][quad][l16]      = lrun0;   // quad-partial sums
    lbuf[w][quad][l16 + 16] = lrun1;
#pragma unroll
    for (int r = 0; r < 4; r++) {
        sm.acc[w][quad * 4 + r][l16]           = acc00[r];
        sm.acc[w][quad * 4 + r + 16][l16]      = acc01[r];
        sm.acc[w][quad * 4 + r][l16 + 16]      = acc10[r];
        sm.acc[w][quad * 4 + r + 16][l16 + 16] = acc11[r];
    }
    __syncthreads();

    // ---- merge 8 waves x 4 quads: 1024 (d,m) elems, two per thread
#pragma unroll
    for (int e = tid; e < DD * 32; e += 512) {
        int d = e >> 5, m = e & 31;
        float M = mbuf[0][m];
#pragma unroll
        for (int s2 = 1; s2 < NSPLIT; s2++) M = fmaxf(M, mbuf[s2][m]);
        float L = 0.f, num = 0.f;
#pragma unroll
        for (int s2 = 0; s2 < NSPLIT; s2++) {
            float e2 = __builtin_amdgcn_exp2f(mbuf[s2][m] - M);
            float lsum = (lbuf[s2][0][m] + lbuf[s2][1][m]) + (lbuf[s2][2][m] + lbuf[s2][3][m]);
            L += lsum * e2;
            num += sm.acc[s2][d][m] * e2;
        }
        vlds[d][m] = num / L;
    }
    __syncthreads();

    // ---- epilogue: D->3 projection + clamp (96 threads)
    if (tid < 96) {
        int m = tid & 31, c = tid >> 5;
        float o = ob[c];
#pragma unroll
        for (int d = 0; d < DD; d++)
            o += ow[c * DD + d] * vlds[d][m];
        o = fminf(1.f, fmaxf(-1.f, o));
        out[((size_t)b * CC + c) * NN + m0 + m] = o;
    }
}

extern "C" void kernel_launch(void* const* d_in, const int* in_sizes, int n_in,
                              void* d_out, int out_size, void* d_ws, size_t ws_size,
                              hipStream_t stream) {
    const float* img = (const float*)d_in[0];
    const float* kw  = (const float*)d_in[1];
    const float* kb  = (const float*)d_in[2];
    const float* qw  = (const float*)d_in[3];
    const float* qb  = (const float*)d_in[4];
    const float* vw  = (const float*)d_in[5];
    const float* vb  = (const float*)d_in[6];
    const float* ow  = (const float*)d_in[7];
    const float* ob  = (const float*)d_in[8];
    float* out = (float*)d_out;

    // Workspace: fH,fL,gH,gL ([B][N][D] fp16) + hV ([B][D][N] fp16) = 5.9 MB
    const size_t sz = (size_t)BB * NN * DD;
    _Float16* fH = (_Float16*)d_ws;
    _Float16* fL = fH + sz;
    _Float16* gH = fL + sz;
    _Float16* gL = gH + sz;
    _Float16* hV = gL + sz;

    prep_kernel<<<576, 256, 0, stream>>>(img, kw, kb, qw, qb, vw, vb, fH, fL, gH, gL, hV);
    attn_kernel<<<BB * (NN / 32), 512, 0, stream>>>(fH, fL, gH, gL, hV, ow, ob, out);
}

// Round 13
// 166.186 us; speedup vs baseline: 1.0808x; 1.0808x over previous
//
#include <hip/hip_runtime.h>
#include <hip/hip_fp16.h>

// Problem constants (B,C,H,W = 2,3,96,96; D=32)
#define BB 2
#define CC 3
#define NN 9216   // 96*96
#define DD 32
#define NSPLIT 8                      // waves per block
#define KSPLIT 2                      // blocks per 32-query group (cross-block split-K)
#define KEYS_PER_WAVE (NN / (KSPLIT * NSPLIT))  // 576
#define CHUNKS (KEYS_PER_WAVE / 64)   // 9
#define NGROUP (BB * NN / 32)         // 576 query groups
#define L2E 1.44269504f

typedef _Float16 half8 __attribute__((ext_vector_type(8)));
typedef _Float16 half4v __attribute__((ext_vector_type(4)));
typedef __fp16 fp16x2 __attribute__((ext_vector_type(2)));
typedef float float4v __attribute__((ext_vector_type(4)));

#define MFMA_K32(a, b, c) __builtin_amdgcn_mfma_f32_16x16x32_f16((a), (b), (c), 0, 0, 0)

// ---------------------------------------------------------------------------
// Fused prep (unchanged from R10). QK hi/lo split, Q pre-scaled by log2(e);
// V as [B][D][N] fp16.
// ---------------------------------------------------------------------------
__global__ __launch_bounds__(256) void prep_kernel(
    const float* __restrict__ img,
    const float* __restrict__ kw, const float* __restrict__ kb,
    const float* __restrict__ qw, const float* __restrict__ qb,
    const float* __restrict__ vw, const float* __restrict__ vb,
    _Float16* __restrict__ fH, _Float16* __restrict__ fL,
    _Float16* __restrict__ gH, _Float16* __restrict__ gL,
    _Float16* __restrict__ hV)
{
    int bid = blockIdx.x;
    if (bid < 288) {
        int id = bid * 256 + threadIdx.x;          // [0, BB*NN*4)
        int part = id & 3;
        int n = (id >> 2) % NN;
        int b = (id >> 2) / NN;
        const float* xb = img + (size_t)b * CC * NN + n;
        float x0 = xb[0], x1 = xb[NN], x2 = xb[2 * NN];
        half8 fh, fl, gh, gl;
#pragma unroll
        for (int j = 0; j < 8; j++) {
            int d = part * 8 + j;
            float fv = kw[d * 3 + 0] * x0 + kw[d * 3 + 1] * x1 + kw[d * 3 + 2] * x2 + kb[d];
            float gv = (qw[d * 3 + 0] * x0 + qw[d * 3 + 1] * x1 + qw[d * 3 + 2] * x2 + qb[d]) * L2E;
            _Float16 fhi = (_Float16)fv;
            _Float16 ghi = (_Float16)gv;
            fh[j] = fhi; fl[j] = (_Float16)(fv - (float)fhi);
            gh[j] = ghi; gl[j] = (_Float16)(gv - (float)ghi);
        }
        size_t off = ((size_t)b * NN + n) * DD + part * 8;
        *(half8*)(fH + off) = fh;
        *(half8*)(fL + off) = fl;
        *(half8*)(gH + off) = gh;
        *(half8*)(gL + off) = gl;
    } else {
        int id = (bid - 288) * 256 + threadIdx.x;  // [0, BB*DD*NN/8)
        const int N8 = NN / 8;
        int n8 = id % N8;
        int d = (id / N8) % DD;
        int b = id / (N8 * DD);
        const float* xb = img + (size_t)b * CC * NN + n8 * 8;
        float w0 = vw[d * 3 + 0], w1 = vw[d * 3 + 1], w2 = vw[d * 3 + 2], bv = vb[d];
        half8 hv;
#pragma unroll
        for (int j = 0; j < 8; j++)
            hv[j] = (_Float16)(w0 * xb[j] + w1 * xb[NN + j] + w2 * xb[2 * NN + j] + bv);
        *(half8*)(hV + (size_t)id * 8) = hv;
    }
}

// ---------------------------------------------------------------------------
// Flash attention PARTIAL, cross-block split-K x2 (grid 1152 = 4.5 blocks/CU
// vs R10's 2.25 — attacks the measured 30% occupancy / packing limit).
// Inner loop identical to R10 (best measured): 2 Q-tiles/wave, 64-key chunks,
// P wave-private in LDS [m][n] stride 72, PV with A=V^T B=P (per-lane stats).
// Block epilogue: LDS-merge its 8 waves -> UN-NORMALIZED partial
// (num[32][32], M[32], L[32]) -> global for the 2-way merge kernel.
// ---------------------------------------------------------------------------
__global__ __launch_bounds__(512, 4) void attn_partial_kernel(
    const _Float16* __restrict__ fH, const _Float16* __restrict__ fL,
    const _Float16* __restrict__ gH, const _Float16* __restrict__ gL,
    const _Float16* __restrict__ hV,
    float* __restrict__ pnum, float* __restrict__ pM, float* __restrict__ pL)
{
    const int gb = blockIdx.x;             // 0 .. NGROUP*KSPLIT-1
    const int g  = gb >> 1;                // query group
    const int ks = gb & 1;                 // key-split id
    const int b = g / (NN / 32);
    const int m0 = (g % (NN / 32)) * 32;
    const int tid = threadIdx.x;
    const int w = tid >> 6;                // wave id 0..7
    const int lane = tid & 63;
    const int l16 = lane & 15;
    const int quad = lane >> 4;

    // Phase union: P staging (36864 B) / merge accumulator (33792 B)
    union SMem {
        _Float16 P[NSPLIT * 2 * 16 * 72];
        float acc[NSPLIT][DD][33];         // [w][d][m]
    };
    __shared__ __align__(16) SMem sm;
    __shared__ float mbuf[NSPLIT][32];     // [w][m]
    __shared__ float lbuf[NSPLIT][4][32];  // [w][quad][m] (quad-partial sums)

    // Q B-fragments for both tiles (hi + lo, log2e-scaled)
    const _Float16* gHb = gH + ((size_t)b * NN + m0 + l16) * DD + quad * 8;
    const _Float16* gLb = gL + ((size_t)b * NN + m0 + l16) * DD + quad * 8;
    half8 qh0 = *(const half8*)(gHb);
    half8 ql0 = *(const half8*)(gLb);
    half8 qh1 = *(const half8*)(gHb + (size_t)16 * DD);
    half8 ql1 = *(const half8*)(gLb + (size_t)16 * DD);

    float4v acc00 = {0,0,0,0}, acc01 = {0,0,0,0};  // tile0: O^T[d=quad*4+r / +16][m=l16]
    float4v acc10 = {0,0,0,0}, acc11 = {0,0,0,0};  // tile1
    float mrun0 = -1e30f, lrun0 = 0.f;             // per-lane col stats (log2 dom.)
    float mrun1 = -1e30f, lrun1 = 0.f;             // lrun = quad-partial sum

    const int nbase = ks * (NN / KSPLIT) + w * KEYS_PER_WAVE;
    const _Float16* hb = hV + (size_t)b * DD * NN;
    const _Float16* vp0 = hb + (size_t)l16 * NN + nbase + quad * 8;        // V^T rows d=l16
    const _Float16* vp1 = hb + (size_t)(l16 + 16) * NN + nbase + quad * 8; // rows d=l16+16
    const _Float16* khp = fH + ((size_t)b * NN + nbase + l16) * DD + quad * 8;
    const _Float16* klp = fL + ((size_t)b * NN + nbase + l16) * DD + quad * 8;
    _Float16* Pw0 = sm.P + (size_t)(w * 2 + 0) * 16 * 72;
    _Float16* Pw1 = sm.P + (size_t)(w * 2 + 1) * 16 * 72;

    for (int c = 0; c < CHUNKS; ++c) {
        // ---- shared K fragments (8 x b128) and V^T fragments (4 x b128)
        half8 ka[4], kl[4];
#pragma unroll
        for (int blk = 0; blk < 4; blk++) {
            ka[blk] = *(const half8*)(khp + (size_t)(c * 64 + blk * 16) * DD);
            kl[blk] = *(const half8*)(klp + (size_t)(c * 64 + blk * 16) * DD);
        }
        half8 v00 = *(const half8*)(vp0 + c * 64);        // d 0..15,  n 0..31
        half8 v01 = *(const half8*)(vp0 + c * 64 + 32);   // d 0..15,  n 32..63
        half8 v10 = *(const half8*)(vp1 + c * 64);        // d 16..31, n 0..31
        half8 v11 = *(const half8*)(vp1 + c * 64 + 32);   // d 16..31, n 32..63

        // ================= tile 0: scores + softmax + P stage =================
        {
            float4v s[4];
#pragma unroll
            for (int blk = 0; blk < 4; blk++) {
                float4v z = {0,0,0,0};
                float4v t = MFMA_K32(ka[blk], ql0, z);
                t = MFMA_K32(kl[blk], qh0, t);
                s[blk] = MFMA_K32(ka[blk], qh0, t);
            }
            float mb0 = fmaxf(fmaxf(s[0][0], s[0][1]), fmaxf(s[0][2], s[0][3]));
            float mb1 = fmaxf(fmaxf(s[1][0], s[1][1]), fmaxf(s[1][2], s[1][3]));
            float mb2 = fmaxf(fmaxf(s[2][0], s[2][1]), fmaxf(s[2][2], s[2][3]));
            float mb3 = fmaxf(fmaxf(s[3][0], s[3][1]), fmaxf(s[3][2], s[3][3]));
            float mx = fmaxf(fmaxf(mb0, mb1), fmaxf(mb2, mb3));
            mx = fmaxf(mx, __shfl_xor(mx, 16, 64));
            mx = fmaxf(mx, __shfl_xor(mx, 32, 64));
            float mnew = fmaxf(mrun0, mx);
            float rsum = 0.f;
#pragma unroll
            for (int blk = 0; blk < 4; blk++) {
                float p0 = __builtin_amdgcn_exp2f(s[blk][0] - mnew);
                float p1 = __builtin_amdgcn_exp2f(s[blk][1] - mnew);
                float p2 = __builtin_amdgcn_exp2f(s[blk][2] - mnew);
                float p3 = __builtin_amdgcn_exp2f(s[blk][3] - mnew);
                union { fp16x2 h2[2]; half4v h4; } u;
                u.h2[0] = __builtin_amdgcn_cvt_pkrtz(p0, p1);
                u.h2[1] = __builtin_amdgcn_cvt_pkrtz(p2, p3);
                *(half4v*)(Pw0 + l16 * 72 + blk * 16 + quad * 4) = u.h4;
                rsum += (p0 + p1) + (p2 + p3);
            }
            if (__any(mnew > mrun0)) {
                float alpha = __builtin_amdgcn_exp2f(mrun0 - mnew);
#pragma unroll
                for (int r = 0; r < 4; r++) { acc00[r] *= alpha; acc01[r] *= alpha; }
                lrun0 = lrun0 * alpha + rsum;
                mrun0 = mnew;
            } else {
                lrun0 += rsum;
            }
        }
        // ================= tile 1: scores + softmax + P stage =================
        {
            float4v s[4];
#pragma unroll
            for (int blk = 0; blk < 4; blk++) {
                float4v z = {0,0,0,0};
                float4v t = MFMA_K32(ka[blk], ql1, z);
                t = MFMA_K32(kl[blk], qh1, t);
                s[blk] = MFMA_K32(ka[blk], qh1, t);
            }
            float mb0 = fmaxf(fmaxf(s[0][0], s[0][1]), fmaxf(s[0][2], s[0][3]));
            float mb1 = fmaxf(fmaxf(s[1][0], s[1][1]), fmaxf(s[1][2], s[1][3]));
            float mb2 = fmaxf(fmaxf(s[2][0], s[2][1]), fmaxf(s[2][2], s[2][3]));
            float mb3 = fmaxf(fmaxf(s[3][0], s[3][1]), fmaxf(s[3][2], s[3][3]));
            float mx = fmaxf(fmaxf(mb0, mb1), fmaxf(mb2, mb3));
            mx = fmaxf(mx, __shfl_xor(mx, 16, 64));
            mx = fmaxf(mx, __shfl_xor(mx, 32, 64));
            float mnew = fmaxf(mrun1, mx);
            float rsum = 0.f;
#pragma unroll
            for (int blk = 0; blk < 4; blk++) {
                float p0 = __builtin_amdgcn_exp2f(s[blk][0] - mnew);
                float p1 = __builtin_amdgcn_exp2f(s[blk][1] - mnew);
                float p2 = __builtin_amdgcn_exp2f(s[blk][2] - mnew);
                float p3 = __builtin_amdgcn_exp2f(s[blk][3] - mnew);
                union { fp16x2 h2[2]; half4v h4; } u;
                u.h2[0] = __builtin_amdgcn_cvt_pkrtz(p0, p1);
                u.h2[1] = __builtin_amdgcn_cvt_pkrtz(p2, p3);
                *(half4v*)(Pw1 + l16 * 72 + blk * 16 + quad * 4) = u.h4;
                rsum += (p0 + p1) + (p2 + p3);
            }
            if (__any(mnew > mrun1)) {
                float alpha = __builtin_amdgcn_exp2f(mrun1 - mnew);
#pragma unroll
                for (int r = 0; r < 4; r++) { acc10[r] *= alpha; acc11[r] *= alpha; }
                lrun1 = lrun1 * alpha + rsum;
                mrun1 = mnew;
            } else {
                lrun1 += rsum;
            }
        }
        // ---- PV: A = V^T (regs), B = P (LDS b128) => C[row=d, col=m=l16]
        {
            half8 pf0 = *(const half8*)(Pw0 + l16 * 72 + quad * 8);        // n 0..31
            half8 pf1 = *(const half8*)(Pw0 + l16 * 72 + 32 + quad * 8);   // n 32..63
            acc00 = MFMA_K32(v00, pf0, acc00);
            acc01 = MFMA_K32(v10, pf0, acc01);
            acc00 = MFMA_K32(v01, pf1, acc00);
            acc01 = MFMA_K32(v11, pf1, acc01);
            half8 qf0 = *(const half8*)(Pw1 + l16 * 72 + quad * 8);
            half8 qf1 = *(const half8*)(Pw1 + l16 * 72 + 32 + quad * 8);
            acc10 = MFMA_K32(v00, qf0, acc10);
            acc11 = MFMA_K32(v10, qf0, acc11);
            acc10 = MFMA_K32(v01, qf1, acc10);
            acc11 = MFMA_K32(v11, qf1, acc11);
        }
    }

    __syncthreads();   // all waves done with sm.P — safe to reuse as sm.acc

    // ---- write per-wave partials (fp32) for the in-block merge
    mbuf[w][l16]            = mrun0;   // quad-redundant, same value
    mbuf[w][l16 + 16]       = mrun1;
    lbuf[w][quad][l16]      = lrun0;   // quad-partial sums
    lbuf[w][quad][l16 + 16] = lrun1;
#pragma unroll
    for (int r = 0; r < 4; r++) {
        sm.acc[w][quad * 4 + r][l16]           = acc00[r];
        sm.acc[w][quad * 4 + r + 16][l16]      = acc01[r];
        sm.acc[w][quad * 4 + r][l16 + 16]      = acc10[r];
        sm.acc[w][quad * 4 + r + 16][l16 + 16] = acc11[r];
    }
    __syncthreads();

    // ---- merge 8 waves x 4 quads -> UN-NORMALIZED block partial -> global
#pragma unroll
    for (int e = tid; e < DD * 32; e += 512) {
        int d = e >> 5, m = e & 31;
        float M = mbuf[0][m];
#pragma unroll
        for (int s2 = 1; s2 < NSPLIT; s2++) M = fmaxf(M, mbuf[s2][m]);
        float L = 0.f, num = 0.f;
#pragma unroll
        for (int s2 = 0; s2 < NSPLIT; s2++) {
            float e2 = __builtin_amdgcn_exp2f(mbuf[s2][m] - M);
            float lsum = (lbuf[s2][0][m] + lbuf[s2][1][m]) + (lbuf[s2][2][m] + lbuf[s2][3][m]);
            L += lsum * e2;
            num += sm.acc[s2][d][m] * e2;
        }
        pnum[(size_t)gb * (DD * 32) + e] = num;
        if (d == 0) { pM[gb * 32 + m] = M; pL[gb * 32 + m] = L; }
    }
}

// ---------------------------------------------------------------------------
// Final merge: combine the KSPLIT=2 block partials per query group (2-way
// log-sum-exp), then D->3 projection + clamp.
// ---------------------------------------------------------------------------
__global__ __launch_bounds__(256) void merge_kernel(
    const float* __restrict__ pnum, const float* __restrict__ pM,
    const float* __restrict__ pL,
    const float* __restrict__ ow, const float* __restrict__ ob,
    float* __restrict__ out)
{
    const int g = blockIdx.x;              // 0 .. NGROUP-1
    const int b = g / (NN / 32);
    const int m0 = (g % (NN / 32)) * 32;
    const int tid = threadIdx.x;
    const int gb0 = g * 2, gb1 = g * 2 + 1;

    __shared__ float vlds[32][DD + 1];     // [m][d]

#pragma unroll
    for (int e = tid; e < DD * 32; e += 256) {
        int d = e >> 5, m = e & 31;
        float M0 = pM[gb0 * 32 + m], M1 = pM[gb1 * 32 + m];
        float M = fmaxf(M0, M1);
        float e0 = __builtin_amdgcn_exp2f(M0 - M);
        float e1 = __builtin_amdgcn_exp2f(M1 - M);
        float L = pL[gb0 * 32 + m] * e0 + pL[gb1 * 32 + m] * e1;
        float num = pnum[(size_t)gb0 * (DD * 32) + e] * e0 +
                    pnum[(size_t)gb1 * (DD * 32) + e] * e1;
        vlds[m][d] = num / L;
    }
    __syncthreads();

    if (tid < 96) {
        int m = tid & 31, c = tid >> 5;
        float o = ob[c];
#pragma unroll
        for (int d = 0; d < DD; d++)
            o += ow[c * DD + d] * vlds[m][d];
        o = fminf(1.f, fmaxf(-1.f, o));
        out[((size_t)b * CC + c) * NN + m0 + m] = o;
    }
}

extern "C" void kernel_launch(void* const* d_in, const int* in_sizes, int n_in,
                              void* d_out, int out_size, void* d_ws, size_t ws_size,
                              hipStream_t stream) {
    const float* img = (const float*)d_in[0];
    const float* kw  = (const float*)d_in[1];
    const float* kb  = (const float*)d_in[2];
    const float* qw  = (const float*)d_in[3];
    const float* qb  = (const float*)d_in[4];
    const float* vw  = (const float*)d_in[5];
    const float* vb  = (const float*)d_in[6];
    const float* ow  = (const float*)d_in[7];
    const float* ob  = (const float*)d_in[8];
    float* out = (float*)d_out;

    // Workspace: fH,fL,gH,gL ([B][N][D] fp16) + hV ([B][D][N] fp16) = 5.9 MB
    // + partials: pnum 1152x1024 fp32 (4.7 MB), pM/pL 1152x32 fp32 (147 KB ea)
    const size_t sz = (size_t)BB * NN * DD;
    _Float16* fH = (_Float16*)d_ws;
    _Float16* fL = fH + sz;
    _Float16* gH = fL + sz;
    _Float16* gL = gH + sz;
    _Float16* hV = gL + sz;
    float* pnum = (float*)(hV + sz);
    float* pM   = pnum + (size_t)NGROUP * KSPLIT * DD * 32;
    float* pL   = pM + (size_t)NGROUP * KSPLIT * 32;

    prep_kernel<<<576, 256, 0, stream>>>(img, kw, kb, qw, qb, vw, vb, fH, fL, gH, gL, hV);
    attn_partial_kernel<<<NGROUP * KSPLIT, 512, 0, stream>>>(fH, fL, gH, gL, hV, pnum, pM, pL);
    merge_kernel<<<NGROUP, 256, 0, stream>>>(pnum, pM, pL, ow, ob, out);
}

// Round 16
// 135.511 us; speedup vs baseline: 1.3255x; 1.2264x over previous
//
#include <hip/hip_runtime.h>
#include <hip/hip_fp16.h>

// Problem constants (B,C,H,W = 2,3,96,96; D=32)
#define BB 2
#define CC 3
#define NN 9216   // 96*96
#define DD 32
#define NSPLIT 8                      // waves per block
#define KSPLIT 2                      // blocks per 32-query group
#define KEYS_PER_WAVE (NN / (KSPLIT * NSPLIT))  // 576
#define CHUNKS (KEYS_PER_WAVE / 64)   // 9
#define NGROUP (BB * NN / 32)         // 576 query groups
#define L2E 1.44269504f

typedef _Float16 half8 __attribute__((ext_vector_type(8)));
typedef _Float16 half4v __attribute__((ext_vector_type(4)));
typedef __fp16 fp16x2 __attribute__((ext_vector_type(2)));
typedef float float4v __attribute__((ext_vector_type(4)));

#define MFMA_K32(a, b, c) __builtin_amdgcn_mfma_f32_16x16x32_f16((a), (b), (c), 0, 0, 0)

// ---------------------------------------------------------------------------
// Fused prep. Blocks [0,288): QK — thread per (b, n, part), hi/lo fp16 split,
// Q pre-scaled by log2(e) (R12-proven). Blocks [288,324): PROJECTED V —
// hP[c][n] = (ow.vw).x + ow.vb for c in 0..2 plus a zero row 3; the 3x3
// cw matrix is computed in-block by 12 threads (exact fold of the output
// projection into V — PV then needs 3 rows instead of 32).
// ---------------------------------------------------------------------------
__global__ __launch_bounds__(256) void prep_kernel(
    const float* __restrict__ img,
    const float* __restrict__ kw, const float* __restrict__ kb,
    const float* __restrict__ qw, const float* __restrict__ qb,
    const float* __restrict__ vw, const float* __restrict__ vb,
    const float* __restrict__ ow,
    _Float16* __restrict__ fH, _Float16* __restrict__ fL,
    _Float16* __restrict__ gH, _Float16* __restrict__ gL,
    _Float16* __restrict__ hP)
{
    __shared__ float cwb[12];
    int bid = blockIdx.x;
    if (bid < 288) {
        int id = bid * 256 + threadIdx.x;          // [0, BB*NN*4)
        int part = id & 3;
        int n = (id >> 2) % NN;
        int b = (id >> 2) / NN;
        const float* xb = img + (size_t)b * CC * NN + n;
        float x0 = xb[0], x1 = xb[NN], x2 = xb[2 * NN];
        half8 fh, fl, gh, gl;
#pragma unroll
        for (int j = 0; j < 8; j++) {
            int d = part * 8 + j;
            float fv = kw[d * 3 + 0] * x0 + kw[d * 3 + 1] * x1 + kw[d * 3 + 2] * x2 + kb[d];
            float gv = (qw[d * 3 + 0] * x0 + qw[d * 3 + 1] * x1 + qw[d * 3 + 2] * x2 + qb[d]) * L2E;
            _Float16 fhi = (_Float16)fv;
            _Float16 ghi = (_Float16)gv;
            fh[j] = fhi; fl[j] = (_Float16)(fv - (float)fhi);
            gh[j] = ghi; gl[j] = (_Float16)(gv - (float)ghi);
        }
        size_t off = ((size_t)b * NN + n) * DD + part * 8;
        *(half8*)(fH + off) = fh;
        *(half8*)(fL + off) = fl;
        *(half8*)(gH + off) = gh;
        *(half8*)(gL + off) = gl;
    } else {
        int t = threadIdx.x;
        if (t < 9) {
            int c = t / 3, k = t % 3;
            float s = 0.f;
#pragma unroll
            for (int d = 0; d < DD; d++) s += ow[c * DD + d] * vw[d * 3 + k];
            cwb[t] = s;
        } else if (t < 12) {
            int c = t - 9;
            float s = 0.f;
#pragma unroll
            for (int d = 0; d < DD; d++) s += ow[c * DD + d] * vb[d];
            cwb[9 + c] = s;
        }
        __syncthreads();
        const int N8 = NN / 8;
        int id = (bid - 288) * 256 + t;            // [0, BB*4*N8) = 9216
        int n8 = id % N8;
        int row = (id / N8) & 3;
        int b = id / (N8 * 4);
        half8 hv = {0, 0, 0, 0, 0, 0, 0, 0};
        if (row < 3) {
            const float* xb = img + (size_t)b * CC * NN + n8 * 8;
            float w0 = cwb[row * 3 + 0], w1 = cwb[row * 3 + 1],
                  w2 = cwb[row * 3 + 2], bv = cwb[9 + row];
#pragma unroll
            for (int j = 0; j < 8; j++)
                hv[j] = (_Float16)(w0 * xb[j] + w1 * xb[NN + j] + w2 * xb[2 * NN + j] + bv);
        }
        *(half8*)(hP + ((size_t)(b * 4 + row)) * NN + n8 * 8) = hv;
    }
}

// ---------------------------------------------------------------------------
// Flash attention PARTIAL, cross-block split-K x2 (R12-proven structure:
// online softmax, 2 Q-tiles/wave, 64-key chunks, P wave-private in LDS
// [m][n] stride 72). PV now uses PROJECTED V (3 real rows + zero pad):
// A = hP^T[c][n] (lane row min(l16,3)), B = P  => C[row=c, col=m=l16];
// 2 MFMAs per tile per chunk (was 4), V loads halved, acc 8 regs (was 16).
// Emits un-normalized (num[3][32], M[32], L[32]) per block for the merge.
// ---------------------------------------------------------------------------
__global__ __launch_bounds__(512, 4) void attn_partial_kernel(
    const _Float16* __restrict__ fH, const _Float16* __restrict__ fL,
    const _Float16* __restrict__ gH, const _Float16* __restrict__ gL,
    const _Float16* __restrict__ hP,
    float* __restrict__ pnum, float* __restrict__ pM, float* __restrict__ pL)
{
    const int gb = blockIdx.x;             // 0 .. NGROUP*KSPLIT-1
    const int g  = gb >> 1;                // query group
    const int ks = gb & 1;                 // key-split id
    const int b = g / (NN / 32);
    const int m0 = (g % (NN / 32)) * 32;
    const int tid = threadIdx.x;
    const int w = tid >> 6;                // wave id 0..7
    const int lane = tid & 63;
    const int l16 = lane & 15;
    const int quad = lane >> 4;

    // Phase union: P staging (36864 B) / merge accumulator (3 rows only)
    union SMem {
        _Float16 P[NSPLIT * 2 * 16 * 72];
        float acc[NSPLIT][CC][33];         // [w][c][m]
    };
    __shared__ __align__(16) SMem sm;
    __shared__ float mbuf[NSPLIT][32];     // [w][m]
    __shared__ float lbuf[NSPLIT][4][32];  // [w][quad][m] (quad-partial sums)

    // Q B-fragments for both tiles (hi + lo, log2e-scaled)
    const _Float16* gHb = gH + ((size_t)b * NN + m0 + l16) * DD + quad * 8;
    const _Float16* gLb = gL + ((size_t)b * NN + m0 + l16) * DD + quad * 8;
    half8 qh0 = *(const half8*)(gHb);
    half8 ql0 = *(const half8*)(gLb);
    half8 qh1 = *(const half8*)(gHb + (size_t)16 * DD);
    half8 ql1 = *(const half8*)(gLb + (size_t)16 * DD);

    float4v acc0 = {0,0,0,0};              // tile0: C[row=c=quad*4+r][m=l16]
    float4v acc1 = {0,0,0,0};              // tile1 (only quad0, r<3 useful)
    float mrun0 = -1e30f, lrun0 = 0.f;     // per-lane col stats (log2 dom.)
    float mrun1 = -1e30f, lrun1 = 0.f;     // lrun = quad-partial sum

    const int nbase = ks * (NN / KSPLIT) + w * KEYS_PER_WAVE;
    // hP^T A-frag pointer: row = min(l16,3) (rows 3..15 read the zero row)
    const int vrow = (l16 < 3) ? l16 : 3;
    const _Float16* vp = hP + ((size_t)(b * 4 + vrow)) * NN + nbase + quad * 8;
    const _Float16* khp = fH + ((size_t)b * NN + nbase + l16) * DD + quad * 8;
    const _Float16* klp = fL + ((size_t)b * NN + nbase + l16) * DD + quad * 8;
    _Float16* Pw0 = sm.P + (size_t)(w * 2 + 0) * 16 * 72;
    _Float16* Pw1 = sm.P + (size_t)(w * 2 + 1) * 16 * 72;

    for (int c = 0; c < CHUNKS; ++c) {
        // ---- shared K fragments (8 x b128) and projected-V frags (2 x b128)
        half8 ka[4], kl[4];
#pragma unroll
        for (int blk = 0; blk < 4; blk++) {
            ka[blk] = *(const half8*)(khp + (size_t)(c * 64 + blk * 16) * DD);
            kl[blk] = *(const half8*)(klp + (size_t)(c * 64 + blk * 16) * DD);
        }
        half8 vA0 = *(const half8*)(vp + c * 64);        // n 0..31
        half8 vA1 = *(const half8*)(vp + c * 64 + 32);   // n 32..63

        // ================= tile 0: scores + softmax + P stage =================
        {
            float4v s[4];
#pragma unroll
            for (int blk = 0; blk < 4; blk++) {
                float4v z = {0,0,0,0};
                float4v t = MFMA_K32(ka[blk], ql0, z);
                t = MFMA_K32(kl[blk], qh0, t);
                s[blk] = MFMA_K32(ka[blk], qh0, t);
            }
            float mb0 = fmaxf(fmaxf(s[0][0], s[0][1]), fmaxf(s[0][2], s[0][3]));
            float mb1 = fmaxf(fmaxf(s[1][0], s[1][1]), fmaxf(s[1][2], s[1][3]));
            float mb2 = fmaxf(fmaxf(s[2][0], s[2][1]), fmaxf(s[2][2], s[2][3]));
            float mb3 = fmaxf(fmaxf(s[3][0], s[3][1]), fmaxf(s[3][2], s[3][3]));
            float mx = fmaxf(fmaxf(mb0, mb1), fmaxf(mb2, mb3));
            mx = fmaxf(mx, __shfl_xor(mx, 16, 64));
            mx = fmaxf(mx, __shfl_xor(mx, 32, 64));
            float mnew = fmaxf(mrun0, mx);
            float rsum = 0.f;
#pragma unroll
            for (int blk = 0; blk < 4; blk++) {
                float p0 = __builtin_amdgcn_exp2f(s[blk][0] - mnew);
                float p1 = __builtin_amdgcn_exp2f(s[blk][1] - mnew);
                float p2 = __builtin_amdgcn_exp2f(s[blk][2] - mnew);
                float p3 = __builtin_amdgcn_exp2f(s[blk][3] - mnew);
                union { fp16x2 h2[2]; half4v h4; } u;
                u.h2[0] = __builtin_amdgcn_cvt_pkrtz(p0, p1);
                u.h2[1] = __builtin_amdgcn_cvt_pkrtz(p2, p3);
                *(half4v*)(Pw0 + l16 * 72 + blk * 16 + quad * 4) = u.h4;
                rsum += (p0 + p1) + (p2 + p3);
            }
            if (__any(mnew > mrun0)) {
                float alpha = __builtin_amdgcn_exp2f(mrun0 - mnew);
#pragma unroll
                for (int r = 0; r < 4; r++) acc0[r] *= alpha;
                lrun0 = lrun0 * alpha + rsum;
                mrun0 = mnew;
            } else {
                lrun0 += rsum;
            }
        }
        // ================= tile 1: scores + softmax + P stage =================
        {
            float4v s[4];
#pragma unroll
            for (int blk = 0; blk < 4; blk++) {
                float4v z = {0,0,0,0};
                float4v t = MFMA_K32(ka[blk], ql1, z);
                t = MFMA_K32(kl[blk], qh1, t);
                s[blk] = MFMA_K32(ka[blk], qh1, t);
            }
            float mb0 = fmaxf(fmaxf(s[0][0], s[0][1]), fmaxf(s[0][2], s[0][3]));
            float mb1 = fmaxf(fmaxf(s[1][0], s[1][1]), fmaxf(s[1][2], s[1][3]));
            float mb2 = fmaxf(fmaxf(s[2][0], s[2][1]), fmaxf(s[2][2], s[2][3]));
            float mb3 = fmaxf(fmaxf(s[3][0], s[3][1]), fmaxf(s[3][2], s[3][3]));
            float mx = fmaxf(fmaxf(mb0, mb1), fmaxf(mb2, mb3));
            mx = fmaxf(mx, __shfl_xor(mx, 16, 64));
            mx = fmaxf(mx, __shfl_xor(mx, 32, 64));
            float mnew = fmaxf(mrun1, mx);
            float rsum = 0.f;
#pragma unroll
            for (int blk = 0; blk < 4; blk++) {
                float p0 = __builtin_amdgcn_exp2f(s[blk][0] - mnew);
                float p1 = __builtin_amdgcn_exp2f(s[blk][1] - mnew);
                float p2 = __builtin_amdgcn_exp2f(s[blk][2] - mnew);
                float p3 = __builtin_amdgcn_exp2f(s[blk][3] - mnew);
                union { fp16x2 h2[2]; half4v h4; } u;
                u.h2[0] = __builtin_amdgcn_cvt_pkrtz(p0, p1);
                u.h2[1] = __builtin_amdgcn_cvt_pkrtz(p2, p3);
                *(half4v*)(Pw1 + l16 * 72 + blk * 16 + quad * 4) = u.h4;
                rsum += (p0 + p1) + (p2 + p3);
            }
            if (__any(mnew > mrun1)) {
                float alpha = __builtin_amdgcn_exp2f(mrun1 - mnew);
#pragma unroll
                for (int r = 0; r < 4; r++) acc1[r] *= alpha;
                lrun1 = lrun1 * alpha + rsum;
                mrun1 = mnew;
            } else {
                lrun1 += rsum;
            }
        }
        // ---- PV: A = hP^T (regs, 3 rows + zero pad), B = P (LDS b128)
        //      => C[row=c, col=m=l16] — per-lane stats, no shuffles
        {
            half8 pf0 = *(const half8*)(Pw0 + l16 * 72 + quad * 8);        // n 0..31
            half8 pf1 = *(const half8*)(Pw0 + l16 * 72 + 32 + quad * 8);   // n 32..63
            acc0 = MFMA_K32(vA0, pf0, acc0);
            acc0 = MFMA_K32(vA1, pf1, acc0);
            half8 qf0 = *(const half8*)(Pw1 + l16 * 72 + quad * 8);
            half8 qf1 = *(const half8*)(Pw1 + l16 * 72 + 32 + quad * 8);
            acc1 = MFMA_K32(vA0, qf0, acc1);
            acc1 = MFMA_K32(vA1, qf1, acc1);
        }
    }

    __syncthreads();   // all waves done with sm.P — safe to reuse as sm.acc

    // ---- write per-wave partials (fp32) for the in-block merge
    mbuf[w][l16]            = mrun0;   // quad-redundant, same value
    mbuf[w][l16 + 16]       = mrun1;
    lbuf[w][quad][l16]      = lrun0;   // quad-partial sums
    lbuf[w][quad][l16 + 16] = lrun1;
    if (quad == 0) {
#pragma unroll
        for (int r = 0; r < 3; r++) {
            sm.acc[w][r][l16]      = acc0[r];   // C rows c=0..2 live in quad 0
            sm.acc[w][r][l16 + 16] = acc1[r];
        }
    }
    __syncthreads();

    // ---- merge 8 waves x 4 quads -> un-normalized block partial -> global
    if (tid < CC * 32) {
        int c = tid >> 5, m = tid & 31;
        float M = mbuf[0][m];
#pragma unroll
        for (int s2 = 1; s2 < NSPLIT; s2++) M = fmaxf(M, mbuf[s2][m]);
        float L = 0.f, num = 0.f;
#pragma unroll
        for (int s2 = 0; s2 < NSPLIT; s2++) {
            float e2 = __builtin_amdgcn_exp2f(mbuf[s2][m] - M);
            float lsum = (lbuf[s2][0][m] + lbuf[s2][1][m]) + (lbuf[s2][2][m] + lbuf[s2][3][m]);
            L += lsum * e2;
            num += sm.acc[s2][c][m] * e2;
        }
        pnum[(size_t)gb * (CC * 32) + tid] = num;
        if (c == 0) { pM[gb * 32 + m] = M; pL[gb * 32 + m] = L; }
    }
}

// ---------------------------------------------------------------------------
// Final merge: 2-way log-sum-exp combine of the block partials, + ob, clamp.
// Projection already folded into V — output is direct.
// ---------------------------------------------------------------------------
__global__ __launch_bounds__(128) void merge_kernel(
    const float* __restrict__ pnum, const float* __restrict__ pM,
    const float* __restrict__ pL, const float* __restrict__ ob,
    float* __restrict__ out)
{
    const int g = blockIdx.x;              // 0 .. NGROUP-1
    const int b = g / (NN / 32);
    const int m0 = (g % (NN / 32)) * 32;
    const int tid = threadIdx.x;
    const int gb0 = g * 2, gb1 = g * 2 + 1;

    if (tid < CC * 32) {
        int c = tid >> 5, m = tid & 31;
        float M0 = pM[gb0 * 32 + m], M1 = pM[gb1 * 32 + m];
        float M = fmaxf(M0, M1);
        float e0 = __builtin_amdgcn_exp2f(M0 - M);
        float e1 = __builtin_amdgcn_exp2f(M1 - M);
        float L = pL[gb0 * 32 + m] * e0 + pL[gb1 * 32 + m] * e1;
        float num = pnum[(size_t)gb0 * (CC * 32) + tid] * e0 +
                    pnum[(size_t)gb1 * (CC * 32) + tid] * e1;
        float o = num / L + ob[c];
        o = fminf(1.f, fmaxf(-1.f, o));
        out[((size_t)b * CC + c) * NN + m0 + m] = o;
    }
}

extern "C" void kernel_launch(void* const* d_in, const int* in_sizes, int n_in,
                              void* d_out, int out_size, void* d_ws, size_t ws_size,
                              hipStream_t stream) {
    const float* img = (const float*)d_in[0];
    const float* kw  = (const float*)d_in[1];
    const float* kb  = (const float*)d_in[2];
    const float* qw  = (const float*)d_in[3];
    const float* qb  = (const float*)d_in[4];
    const float* vw  = (const float*)d_in[5];
    const float* vb  = (const float*)d_in[6];
    const float* ow  = (const float*)d_in[7];
    const float* ob  = (const float*)d_in[8];
    float* out = (float*)d_out;

    // Workspace: fH,fL,gH,gL fp16 (4.7 MB) + hP fp16 [B][4][N] (148 KB)
    // + pnum (442 KB) + pM/pL (147 KB each) ~= 5.6 MB
    const size_t sz = (size_t)BB * NN * DD;
    _Float16* fH = (_Float16*)d_ws;
    _Float16* fL = fH + sz;
    _Float16* gH = fL + sz;
    _Float16* gL = gH + sz;
    _Float16* hP = gL + sz;
    float* pnum = (float*)(hP + (size_t)BB * 4 * NN);
    float* pM   = pnum + (size_t)NGROUP * KSPLIT * CC * 32;
    float* pL   = pM + (size_t)NGROUP * KSPLIT * 32;

    prep_kernel<<<324, 256, 0, stream>>>(img, kw, kb, qw, qb, vw, vb, ow,
                                         fH, fL, gH, gL, hP);
    attn_partial_kernel<<<NGROUP * KSPLIT, 512, 0, stream>>>(
        fH, fL, gH, gL, hP, pnum, pM, pL);
    merge_kernel<<<NGROUP, 128, 0, stream>>>(pnum, pM, pL, ob, out);
}